// Round 2
// baseline (736.887 us; speedup 1.0000x reference)
//
#include <hip/hip_runtime.h>
#include <math.h>

typedef unsigned int u32;
typedef short bf16x8 __attribute__((ext_vector_type(8)));   // 8 bf16 bit-patterns
typedef float f32x4 __attribute__((ext_vector_type(4)));

#define N0V 500000
#define N1V 50000
#define N2V 4096
#define E0V 1280000
#define E1V 40960
#define INF 128
#define HIDF 256
#define OUTF 47

// merged prep kernel block ranges (no x->bf16 conversion: dense0 gathers f32 x directly)
#define HIST_BLOCKS 5160                       // 1,320,960 edges / 256
#define PACKW_BLOCKS 128

__device__ __forceinline__ u32 bf16rne(float f) {
  u32 u = __float_as_uint(f);
  return (u + 0x7fffu + ((u >> 16) & 1u)) >> 16;
}
__device__ __forceinline__ u32 pk2(float lo, float hi) {
  return bf16rne(lo) | (bf16rne(hi) << 16);
}

// ---------------- merged: dst histogram | W0 pack ----------------
__global__ __launch_bounds__(256) void prep_k(
    const int* __restrict__ dst0, const int* __restrict__ dst1,
    int* __restrict__ hist0, int* __restrict__ hist1,
    const float* __restrict__ Wl, const float* __restrict__ Wr,
    u32* __restrict__ Wf) {
  const int b = blockIdx.x;
  const int tid = threadIdx.x;
  if (b < HIST_BLOCKS) {
    int gid = b * 256 + tid;                 // < 1,320,960 exactly
    if (gid < E0V) {
      atomicAdd(&hist0[dst0[gid]], 1);
    } else {
      atomicAdd(&hist1[dst1[gid - E0V]], 1);
    }
  } else {
    // pack stacked [Wl;Wr] (256x256) into B-fragment order for 16x16x32 bf16:
    // lane holds B[k = s*32 + (lane>>4)*8 + j][n = t*16 + (lane&15)], j=0..7
    // layout: Wf[((t*8+s)*64 + lane)*8 + j]
    int gid = (b - HIST_BLOCKS) * 256 + tid;  // 0..32767
    int e0 = 2 * gid;
    int j = e0 & 7;
    int lane = (e0 >> 3) & 63;
    int sq = e0 >> 9;
    int s = sq & 7;
    int t = sq >> 3;
    int n = t * 16 + (lane & 15);
    int k0 = s * 32 + (lane >> 4) * 8 + j;
    float v0 = (k0 < 128) ? Wl[k0 * 256 + n] : Wr[(k0 - 128) * 256 + n];
    float v1 = (k0 + 1 < 128) ? Wl[(k0 + 1) * 256 + n] : Wr[(k0 + 1 - 128) * 256 + n];
    Wf[gid] = pk2(v0, v1);
  }
}

// ---------------- CSR build: prefix scan (single block) ----------------
__global__ __launch_bounds__(1024) void scan_k(
    const int* __restrict__ hist0, const int* __restrict__ hist1,
    int* __restrict__ off0, int* __restrict__ cur0,
    int* __restrict__ off1, int* __restrict__ cur1) {
  __shared__ int sums[1024];
  const int t = threadIdx.x;
  {
    const int N = 50000, C = 49;
    int lo = t * C;
    int hi = lo + C; if (hi > N) hi = N;
    int s = 0;
    for (int i = lo; i < hi; i++) s += hist0[i];
    sums[t] = s;
    __syncthreads();
    for (int off = 1; off < 1024; off <<= 1) {
      int v = (t >= off) ? sums[t - off] : 0;
      __syncthreads();
      sums[t] += v;
      __syncthreads();
    }
    int run = sums[t] - s;
    for (int i = lo; i < hi; i++) {
      off0[i] = run; cur0[i] = run;
      run += hist0[i];
    }
    if (t == 1023) off0[N] = sums[1023];
    __syncthreads();
  }
  {
    const int N = 4096, C = 4;
    int lo = t * C;
    int hi = lo + C; if (hi > N) hi = N;
    int s = 0;
    for (int i = lo; i < hi; i++) s += hist1[i];
    sums[t] = s;
    __syncthreads();
    for (int off = 1; off < 1024; off <<= 1) {
      int v = (t >= off) ? sums[t - off] : 0;
      __syncthreads();
      sums[t] += v;
      __syncthreads();
    }
    int run = sums[t] - s;
    for (int i = lo; i < hi; i++) {
      off1[i] = run; cur1[i] = run;
      run += hist1[i];
    }
    if (t == 1023) off1[N] = sums[1023];
  }
}

// ---------------- CSR build: scatter edge source ids ----------------
__global__ __launch_bounds__(256) void scatteridx_k(
    const int* __restrict__ src0, const int* __restrict__ dst0,
    const int* __restrict__ src1, const int* __restrict__ dst1,
    int* __restrict__ cur0, int* __restrict__ cur1,
    int* __restrict__ esrc0, int* __restrict__ esrc1) {
  int gid = blockIdx.x * 256 + threadIdx.x;
  if (gid < E0V) {
    int pos = atomicAdd(&cur0[dst0[gid]], 1);
    esrc0[pos] = src0[gid];
  } else if (gid < E0V + E1V) {
    int g = gid - E0V;
    int pos = atomicAdd(&cur1[dst1[g]], 1);
    esrc1[pos] = src1[g];
  }
}

// ---------------- layer 0: flat-segment f32 gather-mean + MFMA dense + relu ----------------
// 16 target rows/block, 4 waves; wave w owns rows w*4..w*4+3 whose CSR segments are
// CONTIGUOUS in esrc0. One flat edge loop at constant 16-edge chunks (8-deep/lane,
// 2 edges/step: lane = 32*half + w loads float4 channels 4w..4w+3). Row attribution
// via wave-uniform boundaries: uniform fast path (whole chunk in one row) or masked
// cndmask slow path at boundaries/tail. Edge ids prefetched one chunk ahead.
__global__ __launch_bounds__(256) void dense0_mfma(
    const float* __restrict__ x,
    const int* __restrict__ off0, const int* __restrict__ esrc0,
    const u32* __restrict__ Wf, const float* __restrict__ bl,
    float* __restrict__ h) {
  __shared__ __align__(16) unsigned short A_lds[16][264];
  const int tid = threadIdx.x;
  const int base = blockIdx.x * 16;
  const int wave = __builtin_amdgcn_readfirstlane(tid >> 6);  // wave-uniform
  const int lane = tid & 63;

  // self-features: thread -> row tid>>4, channels (tid&15)*8..+7
  {
    int r = tid >> 4;
    int cg = (tid & 15) * 8;
    const float4* xp = (const float4*)(x + (long long)(base + r) * INF + cg);
    float4 a = xp[0], b = xp[1];
    u32 o[4];
    o[0] = pk2(a.x, a.y); o[1] = pk2(a.z, a.w);
    o[2] = pk2(b.x, b.y); o[3] = pk2(b.z, b.w);
    *(uint4*)&A_lds[r][128 + cg] = *(const uint4*)o;
  }

  const int half = lane >> 5;          // which of the 2 edges in a step
  const int w = lane & 31;             // float4 slot within row: channels 4w..4w+3
  const float4* xr = (const float4*)x; // row stride = 32 float4

  const int r0 = base + wave * 4;
  const int s0 = __builtin_amdgcn_readfirstlane(off0[r0]);
  const int c1 = __builtin_amdgcn_readfirstlane(off0[r0 + 1]) - s0;
  const int c2 = __builtin_amdgcn_readfirstlane(off0[r0 + 2]) - s0;
  const int c3 = __builtin_amdgcn_readfirstlane(off0[r0 + 3]) - s0;
  const int m  = __builtin_amdgcn_readfirstlane(off0[r0 + 4]) - s0;
  const int* e = esrc0 + s0;

  f32x4 acc[4];
#pragma unroll
  for (int q = 0; q < 4; q++) acc[q] = (f32x4){0.f, 0.f, 0.f, 0.f};

#define FASTQ(Q)                                                        \
  {                                                                     \
    float sx = 0.f, sy = 0.f, sz = 0.f, sw = 0.f;                       \
    _Pragma("unroll") for (int u = 0; u < 8; u++) {                     \
      sx += v[u].x; sy += v[u].y; sz += v[u].z; sw += v[u].w;           \
    }                                                                   \
    acc[Q][0] += sx; acc[Q][1] += sy; acc[Q][2] += sz; acc[Q][3] += sw; \
  }

  if (m > 0) {
    const int mm1 = m - 1;
    int cid[8];
    float4 v[8];
    // prologue: edge ids for chunk 0 (per-lane vector loads; clamped in-bounds)
#pragma unroll
    for (int u = 0; u < 8; u++) {
      int t = 2 * u + half;
      cid[u] = e[t < m ? t : mm1];
    }
    for (int j = 0; j < m; j += 16) {
      // issue row loads for current chunk
#pragma unroll
      for (int u = 0; u < 8; u++) v[u] = xr[(long long)cid[u] * 32 + w];
      // prefetch next chunk's edge ids (stay in flight past the vmcnt wait on v[])
      int jn = j + 16;
      if (jn < m) {
#pragma unroll
        for (int u = 0; u < 8; u++) {
          int t = jn + 2 * u + half;
          cid[u] = e[t < m ? t : mm1];
        }
      }
      int jend = j + 16;
      // wave-uniform fast path: whole chunk inside one row's segment
      if (jend <= c1) {
        FASTQ(0)
      } else if (j >= c1 && jend <= c2) {
        FASTQ(1)
      } else if (j >= c2 && jend <= c3) {
        FASTQ(2)
      } else if (j >= c3 && jend <= m) {
        FASTQ(3)
      } else {
        // boundary/tail chunk: per-edge masked accumulate (boundaries wave-uniform,
        // t is per-lane; beyond-m edges masked off in all four segments)
#pragma unroll
        for (int u = 0; u < 8; u++) {
          int t = j + 2 * u + half;
          float fx = v[u].x, fy = v[u].y, fz = v[u].z, fw = v[u].w;
          bool b0 = t < c1;
          bool b1 = (t >= c1) & (t < c2);
          bool b2 = (t >= c2) & (t < c3);
          bool b3 = (t >= c3) & (t < m);
          acc[0][0] += b0 ? fx : 0.f; acc[0][1] += b0 ? fy : 0.f;
          acc[0][2] += b0 ? fz : 0.f; acc[0][3] += b0 ? fw : 0.f;
          acc[1][0] += b1 ? fx : 0.f; acc[1][1] += b1 ? fy : 0.f;
          acc[1][2] += b1 ? fz : 0.f; acc[1][3] += b1 ? fw : 0.f;
          acc[2][0] += b2 ? fx : 0.f; acc[2][1] += b2 ? fy : 0.f;
          acc[2][2] += b2 ? fz : 0.f; acc[2][3] += b2 ? fw : 0.f;
          acc[3][0] += b3 ? fx : 0.f; acc[3][1] += b3 ? fy : 0.f;
          acc[3][2] += b3 ? fz : 0.f; acc[3][3] += b3 ? fw : 0.f;
        }
      }
    }
  }
#undef FASTQ

  // per-row: combine edge-halves, divide by count, pack to bf16 in A_lds cols 0..127
  {
    int cb0 = 0, cb1 = c1, cb2 = c2, cb3 = c3, cb4 = m;
    int nq[4] = {cb1 - cb0, cb2 - cb1, cb3 - cb2, cb4 - cb3};
#pragma unroll
    for (int q = 0; q < 4; q++) {
      float sx = acc[q][0] + __shfl_xor(acc[q][0], 32, 64);
      float sy = acc[q][1] + __shfl_xor(acc[q][1], 32, 64);
      float sz = acc[q][2] + __shfl_xor(acc[q][2], 32, 64);
      float sw = acc[q][3] + __shfl_xor(acc[q][3], 32, 64);
      float rinv = 1.f / fmaxf((float)nq[q], 1.f);
      if (half == 0) {
        uint2 p;
        p.x = pk2(sx * rinv, sy * rinv);
        p.y = pk2(sz * rinv, sw * rinv);
        *(uint2*)&A_lds[wave * 4 + q][4 * w] = p;  // channels 4w..4w+3 as bf16
      }
    }
  }
  __syncthreads();

  // MFMA: A-frag m=lane&15, k = s*32 + (lane>>4)*8 + j
  const int mr = lane & 15;
  const int quad = lane >> 4;
  f32x4 oacc[4];
#pragma unroll
  for (int ti = 0; ti < 4; ti++) oacc[ti] = (f32x4){0.f, 0.f, 0.f, 0.f};

  const bf16x8* Wf8 = (const bf16x8*)Wf;
  for (int s = 0; s < 8; s++) {
    bf16x8 af = *(const bf16x8*)&A_lds[mr][s * 32 + quad * 8];
#pragma unroll
    for (int ti = 0; ti < 4; ti++) {
      int t = wave * 4 + ti;
      bf16x8 bfr = Wf8[(t * 8 + s) * 64 + lane];
      oacc[ti] = __builtin_amdgcn_mfma_f32_16x16x32_bf16(af, bfr, oacc[ti], 0, 0, 0);
    }
  }

  // C/D layout: col = lane&15, row = (lane>>4)*4 + reg
#pragma unroll
  for (int ti = 0; ti < 4; ti++) {
    int t = wave * 4 + ti;
    int n = t * 16 + mr;
    float b = bl[n];
#pragma unroll
    for (int reg = 0; reg < 4; reg++) {
      int row = base + quad * 4 + reg;
      h[(long long)row * HIDF + n] = fmaxf(oacc[ti][reg] + b, 0.0f);
    }
  }
}

// ---------------- layer 1: float4 gather-mean + dense + log_softmax ----------------
__global__ __launch_bounds__(64) void final_fused(
    const float* __restrict__ h, const int* __restrict__ off1,
    const int* __restrict__ esrc1, const float* __restrict__ Wl,
    const float* __restrict__ bl, const float* __restrict__ Wr,
    float* __restrict__ out) {
  __shared__ float a_s[256];
  __shared__ float h_s[256];
  const int i = blockIdx.x;
  const int lane = threadIdx.x;

  int s0 = __builtin_amdgcn_readfirstlane(off1[i]);
  int n  = __builtin_amdgcn_readfirstlane(off1[i + 1]) - s0;
  const int* e = esrc1 + s0;
  const float4* h4 = (const float4*)h;   // row = 64 float4
  float ax = 0.f, ay = 0.f, az = 0.f, aw = 0.f;
  int j = 0;
  for (; j + 4 <= n; j += 4) {
    float4 v[4];
#pragma unroll
    for (int u = 0; u < 4; u++) v[u] = h4[e[j + u] * 64 + lane];
#pragma unroll
    for (int u = 0; u < 4; u++) {
      ax += v[u].x; ay += v[u].y; az += v[u].z; aw += v[u].w;
    }
  }
  for (; j < n; j++) {
    float4 v = h4[e[j] * 64 + lane];
    ax += v.x; ay += v.y; az += v.z; aw += v.w;
  }
  float rinv = 1.f / fmaxf((float)n, 1.f);
  float4 am; am.x = ax * rinv; am.y = ay * rinv; am.z = az * rinv; am.w = aw * rinv;
  ((float4*)a_s)[lane] = am;             // a_s[k] = mean channel k
  ((float4*)h_s)[lane] = h4[i * 64 + lane];
  __syncthreads();

  float val = -INFINITY;
  if (lane < OUTF) {
    float acc = bl[lane];
#pragma unroll 4
    for (int k = 0; k < 256; k++)
      acc += a_s[k] * Wl[k * OUTF + lane] + h_s[k] * Wr[k * OUTF + lane];
    val = acc;
  }

  float mx = val;
  for (int off = 32; off >= 1; off >>= 1) mx = fmaxf(mx, __shfl_xor(mx, off, 64));
  float ex = (lane < OUTF) ? expf(val - mx) : 0.0f;
  float ssum = ex;
  for (int off = 32; off >= 1; off >>= 1) ssum += __shfl_xor(ssum, off, 64);

  if (lane < OUTF) out[i * OUTF + lane] = val - mx - logf(ssum);
}

extern "C" void kernel_launch(void* const* d_in, const int* in_sizes, int n_in,
                              void* d_out, int out_size, void* d_ws, size_t ws_size,
                              hipStream_t stream) {
  const float* x   = (const float*)d_in[0];
  const float* Wl0 = (const float*)d_in[1];
  const float* bl0 = (const float*)d_in[2];
  const float* Wr0 = (const float*)d_in[3];
  const float* Wl1 = (const float*)d_in[4];
  const float* bl1 = (const float*)d_in[5];
  const float* Wr1 = (const float*)d_in[6];
  const int* src0  = (const int*)d_in[7];
  const int* dst0  = (const int*)d_in[8];
  const int* src1  = (const int*)d_in[9];
  const int* dst1  = (const int*)d_in[10];
  float* out = (float*)d_out;

  // workspace layout (bytes):
  //   hist0 @ 0           200,000
  //   hist1 @ 200,064      16,384   (memset covers [0, 216,448))
  //   off0  @ 216,576     200,004
  //   cur0  @ 416,768     200,000
  //   off1  @ 616,960      16,388
  //   cur1  @ 633,600      16,384
  //   esrc0 @ 650,240   5,120,000
  //   esrc1 @ 5,770,240   163,840
  //   h     @ 5,934,080  51,200,000  (end 57,134,080)
  //   Wf0   @ 57,134,080    131,072  (end 57,265,152)
  char* ws = (char*)d_ws;
  int* hist0 = (int*)(ws);
  int* hist1 = (int*)(ws + 200064);
  int* off0  = (int*)(ws + 216576);
  int* cur0  = (int*)(ws + 416768);
  int* off1  = (int*)(ws + 616960);
  int* cur1  = (int*)(ws + 633600);
  int* esrc0 = (int*)(ws + 650240);
  int* esrc1 = (int*)(ws + 5770240);
  float* h   = (float*)(ws + 5934080);
  u32* Wf0   = (u32*)(ws + 57134080);

  hipMemsetAsync(ws, 0, 216448, stream);

  prep_k<<<HIST_BLOCKS + PACKW_BLOCKS, 256, 0, stream>>>(
      dst0, dst1, hist0, hist1, Wl0, Wr0, Wf0);
  scan_k<<<1, 1024, 0, stream>>>(hist0, hist1, off0, cur0, off1, cur1);
  scatteridx_k<<<(E0V + E1V + 255) / 256, 256, 0, stream>>>(
      src0, dst0, src1, dst1, cur0, cur1, esrc0, esrc1);
  dense0_mfma<<<N1V / 16, 256, 0, stream>>>(x, off0, esrc0, Wf0, bl0, h);
  final_fused<<<N2V, 64, 0, stream>>>(h, off1, esrc1, Wl1, bl1, Wr1, out);
}

// Round 3
// 714.246 us; speedup vs baseline: 1.0317x; 1.0317x over previous
//
#include <hip/hip_runtime.h>
#include <math.h>

typedef unsigned int u32;
typedef short bf16x8 __attribute__((ext_vector_type(8)));   // 8 bf16 bit-patterns
typedef float f32x4 __attribute__((ext_vector_type(4)));

#define N0V 500000
#define N1V 50000
#define N2V 4096
#define E0V 1280000
#define E1V 40960
#define INF 128
#define HIDF 256
#define OUTF 47

// merged prep kernel block ranges
#define HIST_BLOCKS 5160                       // 1,320,960 edges / 256
#define PACKW_BLOCKS 128
#define USEDT_BLOCKS 16                        // mark targets 0..4095
#define USEDS_BLOCKS 160                       // mark src1 (40,960)

__device__ __forceinline__ u32 bf16rne(float f) {
  u32 u = __float_as_uint(f);
  return (u + 0x7fffu + ((u >> 16) & 1u)) >> 16;
}
__device__ __forceinline__ u32 pk2(float lo, float hi) {
  return bf16rne(lo) | (bf16rne(hi) << 16);
}

// ---------------- merged: dst histogram | W0 pack | used-row marking ----------------
__global__ __launch_bounds__(256) void prep_k(
    const int* __restrict__ dst0, const int* __restrict__ dst1,
    const int* __restrict__ src1,
    int* __restrict__ hist0, int* __restrict__ hist1, int* __restrict__ used,
    const float* __restrict__ Wl, const float* __restrict__ Wr,
    u32* __restrict__ Wf) {
  const int b = blockIdx.x;
  const int tid = threadIdx.x;
  if (b < HIST_BLOCKS) {
    int gid = b * 256 + tid;                 // < 1,320,960 exactly
    if (gid < E0V) {
      atomicAdd(&hist0[dst0[gid]], 1);
    } else {
      atomicAdd(&hist1[dst1[gid - E0V]], 1);
    }
  } else if (b < HIST_BLOCKS + PACKW_BLOCKS) {
    // pack stacked [Wl;Wr] (256x256) into B-fragment order for 16x16x32 bf16:
    // lane holds B[k = s*32 + (lane>>4)*8 + j][n = t*16 + (lane&15)], j=0..7
    // layout: Wf[((t*8+s)*64 + lane)*8 + j]
    int gid = (b - HIST_BLOCKS) * 256 + tid;  // 0..32767
    int e0 = 2 * gid;
    int j = e0 & 7;
    int lane = (e0 >> 3) & 63;
    int sq = e0 >> 9;
    int s = sq & 7;
    int t = sq >> 3;
    int n = t * 16 + (lane & 15);
    int k0 = s * 32 + (lane >> 4) * 8 + j;
    float v0 = (k0 < 128) ? Wl[k0 * 256 + n] : Wr[(k0 - 128) * 256 + n];
    float v1 = (k0 + 1 < 128) ? Wl[(k0 + 1) * 256 + n] : Wr[(k0 + 1 - 128) * 256 + n];
    Wf[gid] = pk2(v0, v1);
  } else if (b < HIST_BLOCKS + PACKW_BLOCKS + USEDT_BLOCKS) {
    int gid = (b - HIST_BLOCKS - PACKW_BLOCKS) * 256 + tid;   // 0..4095
    used[gid] = 1;
  } else {
    int gid = (b - HIST_BLOCKS - PACKW_BLOCKS - USEDT_BLOCKS) * 256 + tid; // 0..40959
    used[src1[gid]] = 1;
  }
}

// ---------------- CSR build: compacted padded prefix scan (single block) ----------------
// For used rows only: padded count pc = ceil(hist/16)*16. Outputs:
//   map[i]   : original row -> compact index (used rows only)
//   rowof[j] : compact index -> original row
//   poff[j]  : padded CSR offset (compact order), poff[U..U+16] = total
//   cntc[j]  : true edge count of compact row j, cntc[U..U+15] = 0
//   cur0[i]  : scatter cursor (original-row indexed), init poff
//   Ucnt[0]  : number of used rows
__global__ __launch_bounds__(1024) void scan_k(
    const int* __restrict__ hist0, const int* __restrict__ hist1,
    const int* __restrict__ used,
    int* __restrict__ poff, int* __restrict__ cntc,
    int* __restrict__ rowof, int* __restrict__ map,
    int* __restrict__ cur0, int* __restrict__ off1, int* __restrict__ cur1,
    int* __restrict__ Ucnt) {
  __shared__ int sums[1024];
  const int t = threadIdx.x;
  {
    const int N = 50000, C = 49;
    int lo = t * C;
    int hi = lo + C; if (hi > N) hi = N;
    int spc = 0, su = 0;
    for (int i = lo; i < hi; i++) {
      int u = used[i];
      int pc = u ? ((hist0[i] + 15) & ~15) : 0;
      spc += pc; su += u;
    }
    // scan 1: padded counts
    sums[t] = spc;
    __syncthreads();
    for (int off = 1; off < 1024; off <<= 1) {
      int v = (t >= off) ? sums[t - off] : 0;
      __syncthreads();
      sums[t] += v;
      __syncthreads();
    }
    int run_pc = sums[t] - spc;
    int total_pc = sums[1023];
    __syncthreads();
    // scan 2: used counts (compact index)
    sums[t] = su;
    __syncthreads();
    for (int off = 1; off < 1024; off <<= 1) {
      int v = (t >= off) ? sums[t - off] : 0;
      __syncthreads();
      sums[t] += v;
      __syncthreads();
    }
    int run_u = sums[t] - su;
    int U = sums[1023];
    __syncthreads();
    for (int i = lo; i < hi; i++) {
      if (used[i]) {
        int n = hist0[i];
        int pc = (n + 15) & ~15;
        map[i] = run_u;
        rowof[run_u] = i;
        poff[run_u] = run_pc;
        cntc[run_u] = n;
        cur0[i] = run_pc;
        run_pc += pc;
        run_u++;
      }
    }
    if (t == 1023) {
      Ucnt[0] = U;
      for (int k = 0; k <= 16; k++) poff[U + k] = total_pc;
      for (int k = 0; k < 16; k++) cntc[U + k] = 0;
    }
    __syncthreads();
  }
  {
    const int N = 4096, C = 4;
    int lo = t * C;
    int hi = lo + C; if (hi > N) hi = N;
    int s = 0;
    for (int i = lo; i < hi; i++) s += hist1[i];
    sums[t] = s;
    __syncthreads();
    for (int off = 1; off < 1024; off <<= 1) {
      int v = (t >= off) ? sums[t - off] : 0;
      __syncthreads();
      sums[t] += v;
      __syncthreads();
    }
    int run = sums[t] - s;
    for (int i = lo; i < hi; i++) {
      off1[i] = run; cur1[i] = run;
      run += hist1[i];
    }
    if (t == 1023) off1[N] = sums[1023];
  }
}

// ---------------- CSR build: scatter edge source ids ----------------
// layer-0 edges into unused target rows are dropped; layer-1 sources remapped to compact ids.
__global__ __launch_bounds__(256) void scatteridx_k(
    const int* __restrict__ src0, const int* __restrict__ dst0,
    const int* __restrict__ src1, const int* __restrict__ dst1,
    const int* __restrict__ used, const int* __restrict__ map,
    int* __restrict__ cur0, int* __restrict__ cur1,
    int* __restrict__ esrc0, int* __restrict__ esrc1) {
  int gid = blockIdx.x * 256 + threadIdx.x;
  if (gid < E0V) {
    int d = dst0[gid];
    if (used[d]) {
      int pos = atomicAdd(&cur0[d], 1);
      esrc0[pos] = src0[gid];
    }
  } else if (gid < E0V + E1V) {
    int g = gid - E0V;
    int pos = atomicAdd(&cur1[dst1[g]], 1);
    esrc1[pos] = map[src1[g]];
  }
}

// ---------------- layer 0 (used rows only): padded f32 gather-mean + MFMA + relu ----------------
// 16 compact rows/block, 4 waves; wave owns 4 rows whose padded CSR segments are contiguous.
// All segments padded to multiples of 16 with sentinel id 0 (memset); every 16-edge chunk lies
// wholly in one row -> always fast path. Pad contribution removed via sum -= pad * x[0].
// 2 edges/load-step (lane = 32*half + w, float4 = channels 4w..4w+3); chunks double-buffered.
__global__ __launch_bounds__(256) void dense0_mfma(
    const float* __restrict__ x,
    const int* __restrict__ poff, const int* __restrict__ cntc,
    const int* __restrict__ rowof, const int* __restrict__ esrc0,
    const int* __restrict__ Ucnt,
    const u32* __restrict__ Wf, const float* __restrict__ bl,
    float* __restrict__ h) {
  const int U = Ucnt[0];
  const int base = blockIdx.x * 16;
  if (base >= U) return;
  __shared__ __align__(16) unsigned short A_lds[16][264];
  const int tid = threadIdx.x;
  const int wave = __builtin_amdgcn_readfirstlane(tid >> 6);  // wave-uniform
  const int lane = tid & 63;

  // self-features: thread -> compact row tid>>4, channels (tid&15)*8..+7
  {
    int r = tid >> 4;
    int j = base + r;
    int cg = (tid & 15) * 8;
    if (j < U) {
      int row = rowof[j];
      const float4* xp = (const float4*)(x + row * INF + cg);
      float4 a = xp[0], b = xp[1];
      u32 o[4];
      o[0] = pk2(a.x, a.y); o[1] = pk2(a.z, a.w);
      o[2] = pk2(b.x, b.y); o[3] = pk2(b.z, b.w);
      *(uint4*)&A_lds[r][128 + cg] = *(const uint4*)o;
    } else {
      uint4 z = {0u, 0u, 0u, 0u};
      *(uint4*)&A_lds[r][128 + cg] = z;
    }
  }

  const int half = lane >> 5;          // which of the 2 edges in a step
  const int w = lane & 31;             // float4 slot within row: channels 4w..4w+3
  const float4* xr = (const float4*)x; // row stride = 32 float4
  const float4 x0 = xr[w];             // row 0 (sentinel) slot, for pad correction

  const int r0 = base + wave * 4;
  const int p0 = __builtin_amdgcn_readfirstlane(poff[r0]);
  const int c1 = __builtin_amdgcn_readfirstlane(poff[r0 + 1]) - p0;
  const int c2 = __builtin_amdgcn_readfirstlane(poff[r0 + 2]) - p0;
  const int c3 = __builtin_amdgcn_readfirstlane(poff[r0 + 3]) - p0;
  const int m  = __builtin_amdgcn_readfirstlane(poff[r0 + 4]) - p0;
  const int* e = esrc0 + p0;

  f32x4 acc[4];
#pragma unroll
  for (int q = 0; q < 4; q++) acc[q] = (f32x4){0.f, 0.f, 0.f, 0.f};

#define LOADIDS(ID, st)                                                 \
  _Pragma("unroll") for (int u = 0; u < 8; u++) ID[u] = e[(st) + 2 * u + half];
#define ISSUE(V, ID)                                                    \
  _Pragma("unroll") for (int u = 0; u < 8; u++) V[u] = xr[ID[u] * 32 + w];
#define ADDTO(Q, sx, sy, sz, sw_)                                       \
  { acc[Q][0] += sx; acc[Q][1] += sy; acc[Q][2] += sz; acc[Q][3] += sw_; }
#define ACCUM(V, st)                                                    \
  {                                                                     \
    float sx = 0.f, sy = 0.f, sz = 0.f, sw_ = 0.f;                      \
    _Pragma("unroll") for (int u = 0; u < 8; u++) {                     \
      sx += V[u].x; sy += V[u].y; sz += V[u].z; sw_ += V[u].w;          \
    }                                                                   \
    if ((st) < c1) ADDTO(0, sx, sy, sz, sw_)                            \
    else if ((st) < c2) ADDTO(1, sx, sy, sz, sw_)                       \
    else if ((st) < c3) ADDTO(2, sx, sy, sz, sw_)                       \
    else ADDTO(3, sx, sy, sz, sw_)                                      \
  }

  if (m > 0) {
    int iA[8], iB[8];
    float4 vA[8], vB[8];
    const int nch = m >> 4;            // number of 16-edge chunks
    LOADIDS(iA, 0)
    ISSUE(vA, iA)
    if (nch > 1) LOADIDS(iB, 16)
    int cc = 0;
    for (; cc + 2 <= nch; cc += 2) {
      ISSUE(vB, iB)                    // chunk cc+1 rows in flight
      ACCUM(vA, cc * 16)               // consume chunk cc
      if (cc + 2 < nch) {
        LOADIDS(iA, (cc + 2) * 16)
        ISSUE(vA, iA)                  // chunk cc+2 rows in flight
      }
      if (cc + 3 < nch) LOADIDS(iB, (cc + 3) * 16)
      ACCUM(vB, (cc + 1) * 16)         // consume chunk cc+1
    }
    if (cc < nch) ACCUM(vA, cc * 16)   // odd tail (rows already issued)
  }
#undef LOADIDS
#undef ISSUE
#undef ADDTO
#undef ACCUM

  // per-row: combine halves, remove pad contribution, divide by true count, pack bf16
  {
    const int n0 = __builtin_amdgcn_readfirstlane(cntc[r0]);
    const int n1 = __builtin_amdgcn_readfirstlane(cntc[r0 + 1]);
    const int n2 = __builtin_amdgcn_readfirstlane(cntc[r0 + 2]);
    const int n3 = __builtin_amdgcn_readfirstlane(cntc[r0 + 3]);
    int nq[4] = {n0, n1, n2, n3};
    int pq[4] = {c1 - n0, (c2 - c1) - n1, (c3 - c2) - n2, (m - c3) - n3};
#pragma unroll
    for (int q = 0; q < 4; q++) {
      float sx = acc[q][0] + __shfl_xor(acc[q][0], 32, 64);
      float sy = acc[q][1] + __shfl_xor(acc[q][1], 32, 64);
      float sz = acc[q][2] + __shfl_xor(acc[q][2], 32, 64);
      float sw = acc[q][3] + __shfl_xor(acc[q][3], 32, 64);
      float fp = (float)pq[q];
      sx -= fp * x0.x; sy -= fp * x0.y; sz -= fp * x0.z; sw -= fp * x0.w;
      float rinv = 1.f / fmaxf((float)nq[q], 1.f);
      if (half == 0) {
        uint2 p;
        p.x = pk2(sx * rinv, sy * rinv);
        p.y = pk2(sz * rinv, sw * rinv);
        *(uint2*)&A_lds[wave * 4 + q][4 * w] = p;  // channels 4w..4w+3 as bf16
      }
    }
  }
  __syncthreads();

  // MFMA: A-frag m=lane&15, k = s*32 + (lane>>4)*8 + j
  const int mr = lane & 15;
  const int quad = lane >> 4;
  f32x4 oacc[4];
#pragma unroll
  for (int ti = 0; ti < 4; ti++) oacc[ti] = (f32x4){0.f, 0.f, 0.f, 0.f};

  const bf16x8* Wf8 = (const bf16x8*)Wf;
  for (int s = 0; s < 8; s++) {
    bf16x8 af = *(const bf16x8*)&A_lds[mr][s * 32 + quad * 8];
#pragma unroll
    for (int ti = 0; ti < 4; ti++) {
      int t = wave * 4 + ti;
      bf16x8 bfr = Wf8[(t * 8 + s) * 64 + lane];
      oacc[ti] = __builtin_amdgcn_mfma_f32_16x16x32_bf16(af, bfr, oacc[ti], 0, 0, 0);
    }
  }

  // C/D layout: col = lane&15, row = (lane>>4)*4 + reg
#pragma unroll
  for (int ti = 0; ti < 4; ti++) {
    int t = wave * 4 + ti;
    int n = t * 16 + mr;
    float b = bl[n];
#pragma unroll
    for (int reg = 0; reg < 4; reg++) {
      int j = base + quad * 4 + reg;
      if (j < U) h[j * HIDF + n] = fmaxf(oacc[ti][reg] + b, 0.0f);
    }
  }
}

// ---------------- layer 1: float4 gather-mean + dense + log_softmax ----------------
// h is compact; esrc1 already holds compact ids; map[i]=i for i<4096 (targets all used).
__global__ __launch_bounds__(64) void final_fused(
    const float* __restrict__ h, const int* __restrict__ off1,
    const int* __restrict__ esrc1, const float* __restrict__ Wl,
    const float* __restrict__ bl, const float* __restrict__ Wr,
    float* __restrict__ out) {
  __shared__ float a_s[256];
  __shared__ float h_s[256];
  const int i = blockIdx.x;
  const int lane = threadIdx.x;

  int s0 = __builtin_amdgcn_readfirstlane(off1[i]);
  int n  = __builtin_amdgcn_readfirstlane(off1[i + 1]) - s0;
  const int* e = esrc1 + s0;
  const float4* h4 = (const float4*)h;   // row = 64 float4
  float ax = 0.f, ay = 0.f, az = 0.f, aw = 0.f;
  int j = 0;
  for (; j + 4 <= n; j += 4) {
    float4 v[4];
#pragma unroll
    for (int u = 0; u < 4; u++) v[u] = h4[e[j + u] * 64 + lane];
#pragma unroll
    for (int u = 0; u < 4; u++) {
      ax += v[u].x; ay += v[u].y; az += v[u].z; aw += v[u].w;
    }
  }
  for (; j < n; j++) {
    float4 v = h4[e[j] * 64 + lane];
    ax += v.x; ay += v.y; az += v.z; aw += v.w;
  }
  float rinv = 1.f / fmaxf((float)n, 1.f);
  float4 am; am.x = ax * rinv; am.y = ay * rinv; am.z = az * rinv; am.w = aw * rinv;
  ((float4*)a_s)[lane] = am;             // a_s[k] = mean channel k
  ((float4*)h_s)[lane] = h4[i * 64 + lane];
  __syncthreads();

  float val = -INFINITY;
  if (lane < OUTF) {
    float acc = bl[lane];
#pragma unroll 4
    for (int k = 0; k < 256; k++)
      acc += a_s[k] * Wl[k * OUTF + lane] + h_s[k] * Wr[k * OUTF + lane];
    val = acc;
  }

  float mx = val;
  for (int off = 32; off >= 1; off >>= 1) mx = fmaxf(mx, __shfl_xor(mx, off, 64));
  float ex = (lane < OUTF) ? expf(val - mx) : 0.0f;
  float ssum = ex;
  for (int off = 32; off >= 1; off >>= 1) ssum += __shfl_xor(ssum, off, 64);

  if (lane < OUTF) out[i * OUTF + lane] = val - mx - logf(ssum);
}

extern "C" void kernel_launch(void* const* d_in, const int* in_sizes, int n_in,
                              void* d_out, int out_size, void* d_ws, size_t ws_size,
                              hipStream_t stream) {
  const float* x   = (const float*)d_in[0];
  const float* Wl0 = (const float*)d_in[1];
  const float* bl0 = (const float*)d_in[2];
  const float* Wr0 = (const float*)d_in[3];
  const float* Wl1 = (const float*)d_in[4];
  const float* bl1 = (const float*)d_in[5];
  const float* Wr1 = (const float*)d_in[6];
  const int* src0  = (const int*)d_in[7];
  const int* dst0  = (const int*)d_in[8];
  const int* src1  = (const int*)d_in[9];
  const int* dst1  = (const int*)d_in[10];
  float* out = (float*)d_out;

  // workspace layout (bytes):
  //   hist0  @ 0          200,000
  //   hist1  @ 200,064     16,384
  //   used   @ 216,448    200,000
  //   esrc0p @ 416,448  6,800,000   (memset covers [0, 7,216,448) -> pad sentinel 0)
  //   poff   @ 7,216,448  200,068
  //   cntc   @ 7,416,576  200,064
  //   rowof  @ 7,616,640  200,064
  //   map    @ 7,816,704  200,000
  //   cur0   @ 8,016,704  200,000
  //   off1   @ 8,216,704   16,388
  //   cur1   @ 8,233,152   16,384
  //   esrc1  @ 8,249,536  163,840
  //   Ucnt   @ 8,413,376       64
  //   h      @ 8,413,440 51,200,000 (end 59,613,440)
  //   Wf0    @ 59,613,440   131,072 (end 59,744,512)
  char* ws = (char*)d_ws;
  int* hist0 = (int*)(ws);
  int* hist1 = (int*)(ws + 200064);
  int* used  = (int*)(ws + 216448);
  int* esrc0 = (int*)(ws + 416448);
  int* poff  = (int*)(ws + 7216448);
  int* cntc  = (int*)(ws + 7416576);
  int* rowof = (int*)(ws + 7616640);
  int* map   = (int*)(ws + 7816704);
  int* cur0  = (int*)(ws + 8016704);
  int* off1  = (int*)(ws + 8216704);
  int* cur1  = (int*)(ws + 8233152);
  int* esrc1 = (int*)(ws + 8249536);
  int* Ucnt  = (int*)(ws + 8413376);
  float* h   = (float*)(ws + 8413440);
  u32* Wf0   = (u32*)(ws + 59613440);

  hipMemsetAsync(ws, 0, 7216448, stream);

  prep_k<<<HIST_BLOCKS + PACKW_BLOCKS + USEDT_BLOCKS + USEDS_BLOCKS, 256, 0, stream>>>(
      dst0, dst1, src1, hist0, hist1, used, Wl0, Wr0, Wf0);
  scan_k<<<1, 1024, 0, stream>>>(hist0, hist1, used, poff, cntc, rowof, map,
                                 cur0, off1, cur1, Ucnt);
  scatteridx_k<<<(E0V + E1V + 255) / 256, 256, 0, stream>>>(
      src0, dst0, src1, dst1, used, map, cur0, cur1, esrc0, esrc1);
  dense0_mfma<<<N1V / 16, 256, 0, stream>>>(x, poff, cntc, rowof, esrc0, Ucnt,
                                            Wf0, bl0, h);
  final_fused<<<N2V, 64, 0, stream>>>(h, off1, esrc1, Wl1, bl1, Wr1, out);
}

// Round 4
// 541.477 us; speedup vs baseline: 1.3609x; 1.3191x over previous
//
#include <hip/hip_runtime.h>
#include <math.h>

typedef unsigned int u32;
typedef short bf16x8 __attribute__((ext_vector_type(8)));   // 8 bf16 bit-patterns
typedef float f32x4 __attribute__((ext_vector_type(4)));

#define N0V 500000
#define N1V 50000
#define N2V 4096
#define E0V 1280000
#define E1V 40960
#define INF 128
#define HIDF 256
#define OUTF 47

// merged prep kernel block ranges
#define HIST_BLOCKS 5160                       // 1,320,960 edges / 256
#define PACKW_BLOCKS 128
#define USEDT_BLOCKS 16                        // mark targets 0..4095
#define USEDS_BLOCKS 160                       // mark src1 (40,960)

// hierarchical scan geometry
#define NB0 196                                // ceil(50,000 / 256)
#define NB1 16                                 // 4096 / 256

__device__ __forceinline__ u32 bf16rne(float f) {
  u32 u = __float_as_uint(f);
  return (u + 0x7fffu + ((u >> 16) & 1u)) >> 16;
}
__device__ __forceinline__ u32 pk2(float lo, float hi) {
  return bf16rne(lo) | (bf16rne(hi) << 16);
}

// ---------------- merged: dst histogram | W0 pack | used-row marking ----------------
__global__ __launch_bounds__(256) void prep_k(
    const int* __restrict__ dst0, const int* __restrict__ dst1,
    const int* __restrict__ src1,
    int* __restrict__ hist0, int* __restrict__ hist1, int* __restrict__ used,
    const float* __restrict__ Wl, const float* __restrict__ Wr,
    u32* __restrict__ Wf) {
  const int b = blockIdx.x;
  const int tid = threadIdx.x;
  if (b < HIST_BLOCKS) {
    int gid = b * 256 + tid;                 // < 1,320,960 exactly
    if (gid < E0V) {
      atomicAdd(&hist0[dst0[gid]], 1);
    } else {
      atomicAdd(&hist1[dst1[gid - E0V]], 1);
    }
  } else if (b < HIST_BLOCKS + PACKW_BLOCKS) {
    // pack stacked [Wl;Wr] (256x256) into B-fragment order for 16x16x32 bf16:
    // lane holds B[k = s*32 + (lane>>4)*8 + j][n = t*16 + (lane&15)], j=0..7
    // layout: Wf[((t*8+s)*64 + lane)*8 + j]
    int gid = (b - HIST_BLOCKS) * 256 + tid;  // 0..32767
    int e0 = 2 * gid;
    int j = e0 & 7;
    int lane = (e0 >> 3) & 63;
    int sq = e0 >> 9;
    int s = sq & 7;
    int t = sq >> 3;
    int n = t * 16 + (lane & 15);
    int k0 = s * 32 + (lane >> 4) * 8 + j;
    float v0 = (k0 < 128) ? Wl[k0 * 256 + n] : Wr[(k0 - 128) * 256 + n];
    float v1 = (k0 + 1 < 128) ? Wl[(k0 + 1) * 256 + n] : Wr[(k0 + 1 - 128) * 256 + n];
    Wf[gid] = pk2(v0, v1);
  } else if (b < HIST_BLOCKS + PACKW_BLOCKS + USEDT_BLOCKS) {
    int gid = (b - HIST_BLOCKS - PACKW_BLOCKS) * 256 + tid;   // 0..4095
    used[gid] = 1;
  } else {
    int gid = (b - HIST_BLOCKS - PACKW_BLOCKS - USEDT_BLOCKS) * 256 + tid; // 0..40959
    used[src1[gid]] = 1;
  }
}

// ---------------- scan phase 1: per-block partial sums ----------------
__global__ __launch_bounds__(256) void scanpart_k(
    const int* __restrict__ hist0, const int* __restrict__ hist1,
    const int* __restrict__ used,
    int* __restrict__ blkpc, int* __restrict__ blku, int* __restrict__ blk1) {
  __shared__ int sA[256], sB[256];
  const int b = blockIdx.x, t = threadIdx.x;
  if (b < NB0) {
    int i = b * 256 + t;
    int pc = 0, u = 0;
    if (i < N1V) {
      u = used[i];
      pc = u ? ((hist0[i] + 15) & ~15) : 0;
    }
    sA[t] = pc; sB[t] = u;
    __syncthreads();
    for (int off = 128; off > 0; off >>= 1) {
      if (t < off) { sA[t] += sA[t + off]; sB[t] += sB[t + off]; }
      __syncthreads();
    }
    if (t == 0) { blkpc[b] = sA[0]; blku[b] = sB[0]; }
  } else {
    int i = (b - NB0) * 256 + t;               // < 4096
    sA[t] = hist1[i];
    __syncthreads();
    for (int off = 128; off > 0; off >>= 1) {
      if (t < off) sA[t] += sA[t + off];
      __syncthreads();
    }
    if (t == 0) blk1[b - NB0] = sA[0];
  }
}

// ---------------- scan phase 2: apply (ordered compaction, parallel) ----------------
// Ordered compaction keeps map[i] = i for i < 4096 (all targets are used).
__global__ __launch_bounds__(256) void scanapply_k(
    const int* __restrict__ hist0, const int* __restrict__ hist1,
    const int* __restrict__ used,
    const int* __restrict__ blkpc, const int* __restrict__ blku,
    const int* __restrict__ blk1,
    int* __restrict__ poff, int* __restrict__ cntc,
    int* __restrict__ rowof, int* __restrict__ map,
    int* __restrict__ cur0, int* __restrict__ off1, int* __restrict__ cur1,
    int* __restrict__ Ucnt) {
  __shared__ int sA[256], sB[256];
  const int b = blockIdx.x, t = threadIdx.x;
  if (b < NB0) {
    // redundant global scan of the 196 block partials
    sA[t] = (t < NB0) ? blkpc[t] : 0;
    sB[t] = (t < NB0) ? blku[t] : 0;
    __syncthreads();
    for (int off = 1; off < 256; off <<= 1) {
      int va = (t >= off) ? sA[t - off] : 0;
      int vb = (t >= off) ? sB[t - off] : 0;
      __syncthreads();
      sA[t] += va; sB[t] += vb;
      __syncthreads();
    }
    int base_pc = (b > 0) ? sA[b - 1] : 0;
    int base_u  = (b > 0) ? sB[b - 1] : 0;
    int total_pc = sA[255];
    int U = sB[255];
    __syncthreads();
    // block-local scan over this block's 256 rows
    int i = b * 256 + t;
    int u = 0, n = 0, pc = 0;
    if (i < N1V) {
      u = used[i];
      n = u ? hist0[i] : 0;
      pc = u ? ((n + 15) & ~15) : 0;
    }
    sA[t] = pc; sB[t] = u;
    __syncthreads();
    for (int off = 1; off < 256; off <<= 1) {
      int va = (t >= off) ? sA[t - off] : 0;
      int vb = (t >= off) ? sB[t - off] : 0;
      __syncthreads();
      sA[t] += va; sB[t] += vb;
      __syncthreads();
    }
    if (u) {
      int j = base_u + sB[t] - u;              // exclusive prefix
      int p = base_pc + sA[t] - pc;
      map[i] = j;
      rowof[j] = i;
      poff[j] = p;
      cntc[j] = n;
      cur0[i] = p;
    }
    if (b == NB0 - 1 && t == 0) {
      Ucnt[0] = U;
      for (int k = 0; k <= 16; k++) poff[U + k] = total_pc;
      for (int k = 0; k < 16; k++) cntc[U + k] = 0;
    }
  } else {
    int bb = b - NB0;
    sA[t] = (t < NB1) ? blk1[t] : 0;
    __syncthreads();
    for (int off = 1; off < 256; off <<= 1) {
      int va = (t >= off) ? sA[t - off] : 0;
      __syncthreads();
      sA[t] += va;
      __syncthreads();
    }
    int base = (bb > 0) ? sA[bb - 1] : 0;
    int total = sA[255];
    __syncthreads();
    int i = bb * 256 + t;                      // < 4096
    int c = hist1[i];
    sA[t] = c;
    __syncthreads();
    for (int off = 1; off < 256; off <<= 1) {
      int va = (t >= off) ? sA[t - off] : 0;
      __syncthreads();
      sA[t] += va;
      __syncthreads();
    }
    int o = base + sA[t] - c;
    off1[i] = o; cur1[i] = o;
    if (bb == NB1 - 1 && t == 255) off1[N2V] = total;
  }
}

// ---------------- CSR build: scatter edge source ids ----------------
// layer-0 edges into unused target rows are dropped; layer-1 sources remapped to compact ids.
__global__ __launch_bounds__(256) void scatteridx_k(
    const int* __restrict__ src0, const int* __restrict__ dst0,
    const int* __restrict__ src1, const int* __restrict__ dst1,
    const int* __restrict__ used, const int* __restrict__ map,
    int* __restrict__ cur0, int* __restrict__ cur1,
    int* __restrict__ esrc0, int* __restrict__ esrc1) {
  int gid = blockIdx.x * 256 + threadIdx.x;
  if (gid < E0V) {
    int d = dst0[gid];
    if (used[d]) {
      int pos = atomicAdd(&cur0[d], 1);
      esrc0[pos] = src0[gid];
    }
  } else if (gid < E0V + E1V) {
    int g = gid - E0V;
    int pos = atomicAdd(&cur1[dst1[g]], 1);
    esrc1[pos] = map[src1[g]];
  }
}

// ---------------- layer 0 (used rows only): padded f32 gather-mean + MFMA + relu ----------------
// 16 compact rows/block, 4 waves; wave owns 4 rows whose padded CSR segments are contiguous.
// All segments padded to multiples of 16 with sentinel id 0 (memset); every 16-edge chunk lies
// wholly in one row -> always fast path. Pad contribution removed via sum -= pad * x[0].
// 2 edges/load-step (lane = 32*half + w, float4 = channels 4w..4w+3); chunks double-buffered.
__global__ __launch_bounds__(256) void dense0_mfma(
    const float* __restrict__ x,
    const int* __restrict__ poff, const int* __restrict__ cntc,
    const int* __restrict__ rowof, const int* __restrict__ esrc0,
    const int* __restrict__ Ucnt,
    const u32* __restrict__ Wf, const float* __restrict__ bl,
    float* __restrict__ h) {
  const int U = Ucnt[0];
  const int base = blockIdx.x * 16;
  if (base >= U) return;
  __shared__ __align__(16) unsigned short A_lds[16][264];
  const int tid = threadIdx.x;
  const int wave = __builtin_amdgcn_readfirstlane(tid >> 6);  // wave-uniform
  const int lane = tid & 63;

  // self-features: thread -> compact row tid>>4, channels (tid&15)*8..+7
  {
    int r = tid >> 4;
    int j = base + r;
    int cg = (tid & 15) * 8;
    if (j < U) {
      int row = rowof[j];
      const float4* xp = (const float4*)(x + row * INF + cg);
      float4 a = xp[0], b = xp[1];
      u32 o[4];
      o[0] = pk2(a.x, a.y); o[1] = pk2(a.z, a.w);
      o[2] = pk2(b.x, b.y); o[3] = pk2(b.z, b.w);
      *(uint4*)&A_lds[r][128 + cg] = *(const uint4*)o;
    } else {
      uint4 z = {0u, 0u, 0u, 0u};
      *(uint4*)&A_lds[r][128 + cg] = z;
    }
  }

  const int half = lane >> 5;          // which of the 2 edges in a step
  const int w = lane & 31;             // float4 slot within row: channels 4w..4w+3
  const float4* xr = (const float4*)x; // row stride = 32 float4
  const float4 x0 = xr[w];             // row 0 (sentinel) slot, for pad correction

  const int r0 = base + wave * 4;
  const int p0 = __builtin_amdgcn_readfirstlane(poff[r0]);
  const int c1 = __builtin_amdgcn_readfirstlane(poff[r0 + 1]) - p0;
  const int c2 = __builtin_amdgcn_readfirstlane(poff[r0 + 2]) - p0;
  const int c3 = __builtin_amdgcn_readfirstlane(poff[r0 + 3]) - p0;
  const int m  = __builtin_amdgcn_readfirstlane(poff[r0 + 4]) - p0;
  const int* e = esrc0 + p0;

  f32x4 acc[4];
#pragma unroll
  for (int q = 0; q < 4; q++) acc[q] = (f32x4){0.f, 0.f, 0.f, 0.f};

#define LOADIDS(ID, st)                                                 \
  _Pragma("unroll") for (int u = 0; u < 8; u++) ID[u] = e[(st) + 2 * u + half];
#define ISSUE(V, ID)                                                    \
  _Pragma("unroll") for (int u = 0; u < 8; u++) V[u] = xr[ID[u] * 32 + w];
#define ADDTO(Q, sx, sy, sz, sw_)                                       \
  { acc[Q][0] += sx; acc[Q][1] += sy; acc[Q][2] += sz; acc[Q][3] += sw_; }
#define ACCUM(V, st)                                                    \
  {                                                                     \
    float sx = 0.f, sy = 0.f, sz = 0.f, sw_ = 0.f;                      \
    _Pragma("unroll") for (int u = 0; u < 8; u++) {                     \
      sx += V[u].x; sy += V[u].y; sz += V[u].z; sw_ += V[u].w;          \
    }                                                                   \
    if ((st) < c1) ADDTO(0, sx, sy, sz, sw_)                            \
    else if ((st) < c2) ADDTO(1, sx, sy, sz, sw_)                       \
    else if ((st) < c3) ADDTO(2, sx, sy, sz, sw_)                       \
    else ADDTO(3, sx, sy, sz, sw_)                                      \
  }

  if (m > 0) {
    int iA[8], iB[8];
    float4 vA[8], vB[8];
    const int nch = m >> 4;            // number of 16-edge chunks
    LOADIDS(iA, 0)
    ISSUE(vA, iA)
    if (nch > 1) LOADIDS(iB, 16)
    int cc = 0;
    for (; cc + 2 <= nch; cc += 2) {
      ISSUE(vB, iB)                    // chunk cc+1 rows in flight
      ACCUM(vA, cc * 16)               // consume chunk cc
      if (cc + 2 < nch) {
        LOADIDS(iA, (cc + 2) * 16)
        ISSUE(vA, iA)                  // chunk cc+2 rows in flight
      }
      if (cc + 3 < nch) LOADIDS(iB, (cc + 3) * 16)
      ACCUM(vB, (cc + 1) * 16)         // consume chunk cc+1
    }
    if (cc < nch) ACCUM(vA, cc * 16)   // odd tail (rows already issued)
  }
#undef LOADIDS
#undef ISSUE
#undef ADDTO
#undef ACCUM

  // per-row: combine halves, remove pad contribution, divide by true count, pack bf16
  {
    const int n0 = __builtin_amdgcn_readfirstlane(cntc[r0]);
    const int n1 = __builtin_amdgcn_readfirstlane(cntc[r0 + 1]);
    const int n2 = __builtin_amdgcn_readfirstlane(cntc[r0 + 2]);
    const int n3 = __builtin_amdgcn_readfirstlane(cntc[r0 + 3]);
    int nq[4] = {n0, n1, n2, n3};
    int pq[4] = {c1 - n0, (c2 - c1) - n1, (c3 - c2) - n2, (m - c3) - n3};
#pragma unroll
    for (int q = 0; q < 4; q++) {
      float sx = acc[q][0] + __shfl_xor(acc[q][0], 32, 64);
      float sy = acc[q][1] + __shfl_xor(acc[q][1], 32, 64);
      float sz = acc[q][2] + __shfl_xor(acc[q][2], 32, 64);
      float sw = acc[q][3] + __shfl_xor(acc[q][3], 32, 64);
      float fp = (float)pq[q];
      sx -= fp * x0.x; sy -= fp * x0.y; sz -= fp * x0.z; sw -= fp * x0.w;
      float rinv = 1.f / fmaxf((float)nq[q], 1.f);
      if (half == 0) {
        uint2 p;
        p.x = pk2(sx * rinv, sy * rinv);
        p.y = pk2(sz * rinv, sw * rinv);
        *(uint2*)&A_lds[wave * 4 + q][4 * w] = p;  // channels 4w..4w+3 as bf16
      }
    }
  }
  __syncthreads();

  // MFMA: A-frag m=lane&15, k = s*32 + (lane>>4)*8 + j
  const int mr = lane & 15;
  const int quad = lane >> 4;
  f32x4 oacc[4];
#pragma unroll
  for (int ti = 0; ti < 4; ti++) oacc[ti] = (f32x4){0.f, 0.f, 0.f, 0.f};

  const bf16x8* Wf8 = (const bf16x8*)Wf;
  for (int s = 0; s < 8; s++) {
    bf16x8 af = *(const bf16x8*)&A_lds[mr][s * 32 + quad * 8];
#pragma unroll
    for (int ti = 0; ti < 4; ti++) {
      int t = wave * 4 + ti;
      bf16x8 bfr = Wf8[(t * 8 + s) * 64 + lane];
      oacc[ti] = __builtin_amdgcn_mfma_f32_16x16x32_bf16(af, bfr, oacc[ti], 0, 0, 0);
    }
  }

  // C/D layout: col = lane&15, row = (lane>>4)*4 + reg
#pragma unroll
  for (int ti = 0; ti < 4; ti++) {
    int t = wave * 4 + ti;
    int n = t * 16 + mr;
    float b = bl[n];
#pragma unroll
    for (int reg = 0; reg < 4; reg++) {
      int j = base + quad * 4 + reg;
      if (j < U) h[j * HIDF + n] = fmaxf(oacc[ti][reg] + b, 0.0f);
    }
  }
}

// ---------------- layer 1: float4 gather-mean + dense + log_softmax ----------------
// h is compact; esrc1 already holds compact ids; map[i]=i for i<4096 (targets all used).
__global__ __launch_bounds__(64) void final_fused(
    const float* __restrict__ h, const int* __restrict__ off1,
    const int* __restrict__ esrc1, const float* __restrict__ Wl,
    const float* __restrict__ bl, const float* __restrict__ Wr,
    float* __restrict__ out) {
  __shared__ float a_s[256];
  __shared__ float h_s[256];
  const int i = blockIdx.x;
  const int lane = threadIdx.x;

  int s0 = __builtin_amdgcn_readfirstlane(off1[i]);
  int n  = __builtin_amdgcn_readfirstlane(off1[i + 1]) - s0;
  const int* e = esrc1 + s0;
  const float4* h4 = (const float4*)h;   // row = 64 float4
  float ax = 0.f, ay = 0.f, az = 0.f, aw = 0.f;
  int j = 0;
  for (; j + 4 <= n; j += 4) {
    float4 v[4];
#pragma unroll
    for (int u = 0; u < 4; u++) v[u] = h4[e[j + u] * 64 + lane];
#pragma unroll
    for (int u = 0; u < 4; u++) {
      ax += v[u].x; ay += v[u].y; az += v[u].z; aw += v[u].w;
    }
  }
  for (; j < n; j++) {
    float4 v = h4[e[j] * 64 + lane];
    ax += v.x; ay += v.y; az += v.z; aw += v.w;
  }
  float rinv = 1.f / fmaxf((float)n, 1.f);
  float4 am; am.x = ax * rinv; am.y = ay * rinv; am.z = az * rinv; am.w = aw * rinv;
  ((float4*)a_s)[lane] = am;             // a_s[k] = mean channel k
  ((float4*)h_s)[lane] = h4[i * 64 + lane];
  __syncthreads();

  float val = -INFINITY;
  if (lane < OUTF) {
    float acc = bl[lane];
#pragma unroll 4
    for (int k = 0; k < 256; k++)
      acc += a_s[k] * Wl[k * OUTF + lane] + h_s[k] * Wr[k * OUTF + lane];
    val = acc;
  }

  float mx = val;
  for (int off = 32; off >= 1; off >>= 1) mx = fmaxf(mx, __shfl_xor(mx, off, 64));
  float ex = (lane < OUTF) ? expf(val - mx) : 0.0f;
  float ssum = ex;
  for (int off = 32; off >= 1; off >>= 1) ssum += __shfl_xor(ssum, off, 64);

  if (lane < OUTF) out[i * OUTF + lane] = val - mx - logf(ssum);
}

extern "C" void kernel_launch(void* const* d_in, const int* in_sizes, int n_in,
                              void* d_out, int out_size, void* d_ws, size_t ws_size,
                              hipStream_t stream) {
  const float* x   = (const float*)d_in[0];
  const float* Wl0 = (const float*)d_in[1];
  const float* bl0 = (const float*)d_in[2];
  const float* Wr0 = (const float*)d_in[3];
  const float* Wl1 = (const float*)d_in[4];
  const float* bl1 = (const float*)d_in[5];
  const float* Wr1 = (const float*)d_in[6];
  const int* src0  = (const int*)d_in[7];
  const int* dst0  = (const int*)d_in[8];
  const int* src1  = (const int*)d_in[9];
  const int* dst1  = (const int*)d_in[10];
  float* out = (float*)d_out;

  // workspace layout (bytes):
  //   hist0  @ 0          200,000
  //   hist1  @ 200,064     16,384
  //   used   @ 216,448    200,000
  //   esrc0p @ 416,448  6,800,000   (memset covers [0, 7,216,448) -> pad sentinel 0)
  //   poff   @ 7,216,448  200,068
  //   cntc   @ 7,416,576  200,064
  //   rowof  @ 7,616,640  200,064
  //   map    @ 7,816,704  200,000
  //   cur0   @ 8,016,704  200,000
  //   off1   @ 8,216,704   16,388
  //   cur1   @ 8,233,152   16,384
  //   esrc1  @ 8,249,536  163,840
  //   Ucnt   @ 8,413,376       64
  //   blkpc  @ 8,413,440    1,024
  //   blku   @ 8,414,464    1,024
  //   blk1   @ 8,415,488      128
  //   h      @ 8,416,640 51,200,000 (end 59,616,640)
  //   Wf0    @ 59,616,640   131,072 (end 59,747,712)
  char* ws = (char*)d_ws;
  int* hist0 = (int*)(ws);
  int* hist1 = (int*)(ws + 200064);
  int* used  = (int*)(ws + 216448);
  int* esrc0 = (int*)(ws + 416448);
  int* poff  = (int*)(ws + 7216448);
  int* cntc  = (int*)(ws + 7416576);
  int* rowof = (int*)(ws + 7616640);
  int* map   = (int*)(ws + 7816704);
  int* cur0  = (int*)(ws + 8016704);
  int* off1  = (int*)(ws + 8216704);
  int* cur1  = (int*)(ws + 8233152);
  int* esrc1 = (int*)(ws + 8249536);
  int* Ucnt  = (int*)(ws + 8413376);
  int* blkpc = (int*)(ws + 8413440);
  int* blku  = (int*)(ws + 8414464);
  int* blk1  = (int*)(ws + 8415488);
  float* h   = (float*)(ws + 8416640);
  u32* Wf0   = (u32*)(ws + 59616640);

  hipMemsetAsync(ws, 0, 7216448, stream);

  prep_k<<<HIST_BLOCKS + PACKW_BLOCKS + USEDT_BLOCKS + USEDS_BLOCKS, 256, 0, stream>>>(
      dst0, dst1, src1, hist0, hist1, used, Wl0, Wr0, Wf0);
  scanpart_k<<<NB0 + NB1, 256, 0, stream>>>(hist0, hist1, used, blkpc, blku, blk1);
  scanapply_k<<<NB0 + NB1, 256, 0, stream>>>(hist0, hist1, used, blkpc, blku, blk1,
                                             poff, cntc, rowof, map, cur0, off1, cur1,
                                             Ucnt);
  scatteridx_k<<<(E0V + E1V + 255) / 256, 256, 0, stream>>>(
      src0, dst0, src1, dst1, used, map, cur0, cur1, esrc0, esrc1);
  dense0_mfma<<<N1V / 16, 256, 0, stream>>>(x, poff, cntc, rowof, esrc0, Ucnt,
                                            Wf0, bl0, h);
  final_fused<<<N2V, 64, 0, stream>>>(h, off1, esrc1, Wl1, bl1, Wr1, out);
}

// Round 6
// 530.959 us; speedup vs baseline: 1.3878x; 1.0198x over previous
//
#include <hip/hip_runtime.h>
#include <math.h>

typedef unsigned int u32;
typedef short bf16x8 __attribute__((ext_vector_type(8)));   // 8 bf16 bit-patterns
typedef float f32x4 __attribute__((ext_vector_type(4)));

#define N0V 500000
#define N1V 50000
#define N2V 4096
#define E0V 1280000
#define E1V 40960
#define INF 128
#define HIDF 256
#define OUTF 47

// merged prep kernel block ranges
#define HIST_BLOCKS 5160                       // 1,320,960 edges / 256
#define PACKW_BLOCKS 128
#define USEDT_BLOCKS 16                        // mark targets 0..4095
#define USEDS_BLOCKS 160                       // mark src1 (40,960)

// hierarchical scan geometry
#define NB0 196                                // ceil(50,000 / 256)
#define NB1 16                                 // 4096 / 256

__device__ __forceinline__ u32 bf16rne(float f) {
  u32 u = __float_as_uint(f);
  return (u + 0x7fffu + ((u >> 16) & 1u)) >> 16;
}
__device__ __forceinline__ u32 pk2(float lo, float hi) {
  return bf16rne(lo) | (bf16rne(hi) << 16);
}

// ---------------- merged: dst histogram | W0 pack | used-row marking ----------------
__global__ __launch_bounds__(256) void prep_k(
    const int* __restrict__ dst0, const int* __restrict__ dst1,
    const int* __restrict__ src1,
    int* __restrict__ hist0, int* __restrict__ hist1, int* __restrict__ used,
    const float* __restrict__ Wl, const float* __restrict__ Wr,
    u32* __restrict__ Wf) {
  const int b = blockIdx.x;
  const int tid = threadIdx.x;
  if (b < HIST_BLOCKS) {
    int gid = b * 256 + tid;                 // < 1,320,960 exactly
    if (gid < E0V) {
      atomicAdd(&hist0[dst0[gid]], 1);
    } else {
      atomicAdd(&hist1[dst1[gid - E0V]], 1);
    }
  } else if (b < HIST_BLOCKS + PACKW_BLOCKS) {
    // pack stacked [Wl;Wr] (256x256) into B-fragment order for 16x16x32 bf16:
    // lane holds B[k = s*32 + (lane>>4)*8 + j][n = t*16 + (lane&15)], j=0..7
    // layout: Wf[((t*8+s)*64 + lane)*8 + j]
    int gid = (b - HIST_BLOCKS) * 256 + tid;  // 0..32767
    int e0 = 2 * gid;
    int j = e0 & 7;
    int lane = (e0 >> 3) & 63;
    int sq = e0 >> 9;
    int s = sq & 7;
    int t = sq >> 3;
    int n = t * 16 + (lane & 15);
    int k0 = s * 32 + (lane >> 4) * 8 + j;
    float v0 = (k0 < 128) ? Wl[k0 * 256 + n] : Wr[(k0 - 128) * 256 + n];
    float v1 = (k0 + 1 < 128) ? Wl[(k0 + 1) * 256 + n] : Wr[(k0 + 1 - 128) * 256 + n];
    Wf[gid] = pk2(v0, v1);
  } else if (b < HIST_BLOCKS + PACKW_BLOCKS + USEDT_BLOCKS) {
    int gid = (b - HIST_BLOCKS - PACKW_BLOCKS) * 256 + tid;   // 0..4095
    used[gid] = 1;
  } else {
    int gid = (b - HIST_BLOCKS - PACKW_BLOCKS - USEDT_BLOCKS) * 256 + tid; // 0..40959
    used[src1[gid]] = 1;
  }
}

// ---------------- scan phase 1: per-block partial sums ----------------
__global__ __launch_bounds__(256) void scanpart_k(
    const int* __restrict__ hist0, const int* __restrict__ hist1,
    const int* __restrict__ used,
    int* __restrict__ blkpc, int* __restrict__ blku, int* __restrict__ blk1) {
  __shared__ int sA[256], sB[256];
  const int b = blockIdx.x, t = threadIdx.x;
  if (b < NB0) {
    int i = b * 256 + t;
    int pc = 0, u = 0;
    if (i < N1V) {
      u = used[i];
      pc = u ? ((hist0[i] + 15) & ~15) : 0;
    }
    sA[t] = pc; sB[t] = u;
    __syncthreads();
    for (int off = 128; off > 0; off >>= 1) {
      if (t < off) { sA[t] += sA[t + off]; sB[t] += sB[t + off]; }
      __syncthreads();
    }
    if (t == 0) { blkpc[b] = sA[0]; blku[b] = sB[0]; }
  } else {
    int i = (b - NB0) * 256 + t;               // < 4096
    sA[t] = hist1[i];
    __syncthreads();
    for (int off = 128; off > 0; off >>= 1) {
      if (t < off) sA[t] += sA[t + off];
      __syncthreads();
    }
    if (t == 0) blk1[b - NB0] = sA[0];
  }
}

// ---------------- scan phase 2: apply (ordered compaction, parallel) ----------------
// Ordered compaction keeps map[i] = i for i < 4096 (all targets are used).
// Also writes the pad sentinel ids (0) for each used row's [n, pc) slots, so no
// large memset of esrc0 is needed.
__global__ __launch_bounds__(256) void scanapply_k(
    const int* __restrict__ hist0, const int* __restrict__ hist1,
    const int* __restrict__ used,
    const int* __restrict__ blkpc, const int* __restrict__ blku,
    const int* __restrict__ blk1,
    int* __restrict__ poff, int* __restrict__ cntc,
    int* __restrict__ rowof, int* __restrict__ map,
    int* __restrict__ cur0, int* __restrict__ off1, int* __restrict__ cur1,
    int* __restrict__ Ucnt, int* __restrict__ esrc0) {
  __shared__ int sA[256], sB[256];
  const int b = blockIdx.x, t = threadIdx.x;
  if (b < NB0) {
    // redundant global scan of the 196 block partials
    sA[t] = (t < NB0) ? blkpc[t] : 0;
    sB[t] = (t < NB0) ? blku[t] : 0;
    __syncthreads();
    for (int off = 1; off < 256; off <<= 1) {
      int va = (t >= off) ? sA[t - off] : 0;
      int vb = (t >= off) ? sB[t - off] : 0;
      __syncthreads();
      sA[t] += va; sB[t] += vb;
      __syncthreads();
    }
    int base_pc = (b > 0) ? sA[b - 1] : 0;
    int base_u  = (b > 0) ? sB[b - 1] : 0;
    int total_pc = sA[255];
    int U = sB[255];
    __syncthreads();
    // block-local scan over this block's 256 rows
    int i = b * 256 + t;
    int u = 0, n = 0, pc = 0;
    if (i < N1V) {
      u = used[i];
      n = u ? hist0[i] : 0;
      pc = u ? ((n + 15) & ~15) : 0;
    }
    sA[t] = pc; sB[t] = u;
    __syncthreads();
    for (int off = 1; off < 256; off <<= 1) {
      int va = (t >= off) ? sA[t - off] : 0;
      int vb = (t >= off) ? sB[t - off] : 0;
      __syncthreads();
      sA[t] += va; sB[t] += vb;
      __syncthreads();
    }
    if (u) {
      int j = base_u + sB[t] - u;              // exclusive prefix
      int p = base_pc + sA[t] - pc;
      map[i] = j;
      rowof[j] = i;
      poff[j] = p;
      cntc[j] = n;
      cur0[i] = p;
      for (int k = n; k < pc; k++) esrc0[p + k] = 0;   // pad sentinel ids
    }
    if (b == NB0 - 1 && t == 0) {
      Ucnt[0] = U;
      for (int k = 0; k <= 16; k++) poff[U + k] = total_pc;
      for (int k = 0; k < 16; k++) cntc[U + k] = 0;
    }
  } else {
    int bb = b - NB0;
    sA[t] = (t < NB1) ? blk1[t] : 0;
    __syncthreads();
    for (int off = 1; off < 256; off <<= 1) {
      int va = (t >= off) ? sA[t - off] : 0;
      __syncthreads();
      sA[t] += va;
      __syncthreads();
    }
    int base = (bb > 0) ? sA[bb - 1] : 0;
    int total = sA[255];
    __syncthreads();
    int i = bb * 256 + t;                      // < 4096
    int c = hist1[i];
    sA[t] = c;
    __syncthreads();
    for (int off = 1; off < 256; off <<= 1) {
      int va = (t >= off) ? sA[t - off] : 0;
      __syncthreads();
      sA[t] += va;
      __syncthreads();
    }
    int o = base + sA[t] - c;
    off1[i] = o; cur1[i] = o;
    if (bb == NB1 - 1 && t == 255) off1[N2V] = total;
  }
}

// ---------------- CSR build: scatter edge source ids ----------------
// layer-0 edges into unused target rows are dropped; layer-1 sources remapped to compact ids.
__global__ __launch_bounds__(256) void scatteridx_k(
    const int* __restrict__ src0, const int* __restrict__ dst0,
    const int* __restrict__ src1, const int* __restrict__ dst1,
    const int* __restrict__ used, const int* __restrict__ map,
    int* __restrict__ cur0, int* __restrict__ cur1,
    int* __restrict__ esrc0, int* __restrict__ esrc1) {
  int gid = blockIdx.x * 256 + threadIdx.x;
  if (gid < E0V) {
    int d = dst0[gid];
    if (used[d]) {
      int pos = atomicAdd(&cur0[d], 1);
      esrc0[pos] = src0[gid];
    }
  } else if (gid < E0V + E1V) {
    int g = gid - E0V;
    int pos = atomicAdd(&cur1[dst1[g]], 1);
    esrc1[pos] = map[src1[g]];
  }
}

// ---------------- layer 0 (used rows only): padded f32 gather-mean + MFMA + relu ----------------
// 16 compact rows/block, 4 waves; wave owns 4 rows whose padded CSR segments are contiguous.
// All segments padded to multiples of 16 with sentinel id 0 (written by scanapply_k); every
// 16-edge chunk lies wholly in one row -> always fast path. Pad contribution removed via
// sum -= pad * x[0]. 2 edges/load-step (lane = 32*half + w, float4 = channels 4w..4w+3);
// chunks double-buffered. Self-feature loads issued early, LDS write deferred.
__global__ __launch_bounds__(256) void dense0_mfma(
    const float* __restrict__ x,
    const int* __restrict__ poff, const int* __restrict__ cntc,
    const int* __restrict__ rowof, const int* __restrict__ esrc0,
    const int* __restrict__ Ucnt,
    const u32* __restrict__ Wf, const float* __restrict__ bl,
    float* __restrict__ h) {
  const int U = Ucnt[0];
  const int base = blockIdx.x * 16;
  if (base >= U) return;
  __shared__ __align__(16) unsigned short A_lds[16][264];
  const int tid = threadIdx.x;
  const int wave = __builtin_amdgcn_readfirstlane(tid >> 6);  // wave-uniform
  const int lane = tid & 63;

  // self-features: issue loads now, write LDS after the gather loop
  const int r_self = tid >> 4;
  const int cg = (tid & 15) * 8;
  const bool shave = (base + r_self) < U;
  float4 sfa, sfb;
  if (shave) {
    int row = rowof[base + r_self];
    const float4* xp = (const float4*)(x + row * INF + cg);
    sfa = xp[0]; sfb = xp[1];
  }

  const int half = lane >> 5;          // which of the 2 edges in a step
  const int w = lane & 31;             // float4 slot within row: channels 4w..4w+3
  const float4* xr = (const float4*)x; // row stride = 32 float4
  const float4 x0 = xr[w];             // row 0 (sentinel) slot, for pad correction

  const int r0 = base + wave * 4;
  const int p0 = __builtin_amdgcn_readfirstlane(poff[r0]);
  const int c1 = __builtin_amdgcn_readfirstlane(poff[r0 + 1]) - p0;
  const int c2 = __builtin_amdgcn_readfirstlane(poff[r0 + 2]) - p0;
  const int c3 = __builtin_amdgcn_readfirstlane(poff[r0 + 3]) - p0;
  const int m  = __builtin_amdgcn_readfirstlane(poff[r0 + 4]) - p0;
  const int* e = esrc0 + p0;

  f32x4 acc[4];
#pragma unroll
  for (int q = 0; q < 4; q++) acc[q] = (f32x4){0.f, 0.f, 0.f, 0.f};

#define LOADIDS(ID, st)                                                 \
  _Pragma("unroll") for (int u = 0; u < 8; u++) ID[u] = e[(st) + 2 * u + half];
#define ISSUE(V, ID)                                                    \
  _Pragma("unroll") for (int u = 0; u < 8; u++) V[u] = xr[ID[u] * 32 + w];
#define ADDTO(Q, sx, sy, sz, sw_)                                       \
  { acc[Q][0] += sx; acc[Q][1] += sy; acc[Q][2] += sz; acc[Q][3] += sw_; }
#define ACCUM(V, st)                                                    \
  {                                                                     \
    float sx = 0.f, sy = 0.f, sz = 0.f, sw_ = 0.f;                      \
    _Pragma("unroll") for (int u = 0; u < 8; u++) {                     \
      sx += V[u].x; sy += V[u].y; sz += V[u].z; sw_ += V[u].w;          \
    }                                                                   \
    if ((st) < c1) ADDTO(0, sx, sy, sz, sw_)                            \
    else if ((st) < c2) ADDTO(1, sx, sy, sz, sw_)                       \
    else if ((st) < c3) ADDTO(2, sx, sy, sz, sw_)                       \
    else ADDTO(3, sx, sy, sz, sw_)                                      \
  }

  if (m > 0) {
    int iA[8], iB[8];
    float4 vA[8], vB[8];
    const int nch = m >> 4;            // number of 16-edge chunks
    LOADIDS(iA, 0)
    ISSUE(vA, iA)
    if (nch > 1) LOADIDS(iB, 16)
    int cc = 0;
    for (; cc + 2 <= nch; cc += 2) {
      ISSUE(vB, iB)                    // chunk cc+1 rows in flight
      ACCUM(vA, cc * 16)               // consume chunk cc
      if (cc + 2 < nch) {
        LOADIDS(iA, (cc + 2) * 16)
        ISSUE(vA, iA)                  // chunk cc+2 rows in flight
      }
      if (cc + 3 < nch) LOADIDS(iB, (cc + 3) * 16)
      ACCUM(vB, (cc + 1) * 16)         // consume chunk cc+1
    }
    if (cc < nch) ACCUM(vA, cc * 16)   // odd tail (rows already issued)
  }
#undef LOADIDS
#undef ISSUE
#undef ADDTO
#undef ACCUM

  // deferred self-feature LDS write
  if (shave) {
    u32 o[4];
    o[0] = pk2(sfa.x, sfa.y); o[1] = pk2(sfa.z, sfa.w);
    o[2] = pk2(sfb.x, sfb.y); o[3] = pk2(sfb.z, sfb.w);
    *(uint4*)&A_lds[r_self][128 + cg] = *(const uint4*)o;
  } else {
    uint4 z = {0u, 0u, 0u, 0u};
    *(uint4*)&A_lds[r_self][128 + cg] = z;
  }

  // per-row: combine halves, remove pad contribution, divide by true count, pack bf16
  {
    const int n0 = __builtin_amdgcn_readfirstlane(cntc[r0]);
    const int n1 = __builtin_amdgcn_readfirstlane(cntc[r0 + 1]);
    const int n2 = __builtin_amdgcn_readfirstlane(cntc[r0 + 2]);
    const int n3 = __builtin_amdgcn_readfirstlane(cntc[r0 + 3]);
    int nq[4] = {n0, n1, n2, n3};
    int pq[4] = {c1 - n0, (c2 - c1) - n1, (c3 - c2) - n2, (m - c3) - n3};
#pragma unroll
    for (int q = 0; q < 4; q++) {
      float sx = acc[q][0] + __shfl_xor(acc[q][0], 32, 64);
      float sy = acc[q][1] + __shfl_xor(acc[q][1], 32, 64);
      float sz = acc[q][2] + __shfl_xor(acc[q][2], 32, 64);
      float sw = acc[q][3] + __shfl_xor(acc[q][3], 32, 64);
      float fp = (float)pq[q];
      sx -= fp * x0.x; sy -= fp * x0.y; sz -= fp * x0.z; sw -= fp * x0.w;
      float rinv = 1.f / fmaxf((float)nq[q], 1.f);
      if (half == 0) {
        uint2 p;
        p.x = pk2(sx * rinv, sy * rinv);
        p.y = pk2(sz * rinv, sw * rinv);
        *(uint2*)&A_lds[wave * 4 + q][4 * w] = p;  // channels 4w..4w+3 as bf16
      }
    }
  }
  __syncthreads();

  // MFMA: A-frag m=lane&15, k = s*32 + (lane>>4)*8 + j
  const int mr = lane & 15;
  const int quad = lane >> 4;
  f32x4 oacc[4];
#pragma unroll
  for (int ti = 0; ti < 4; ti++) oacc[ti] = (f32x4){0.f, 0.f, 0.f, 0.f};

  const bf16x8* Wf8 = (const bf16x8*)Wf;
  for (int s = 0; s < 8; s++) {
    bf16x8 af = *(const bf16x8*)&A_lds[mr][s * 32 + quad * 8];
#pragma unroll
    for (int ti = 0; ti < 4; ti++) {
      int t = wave * 4 + ti;
      bf16x8 bfr = Wf8[(t * 8 + s) * 64 + lane];
      oacc[ti] = __builtin_amdgcn_mfma_f32_16x16x32_bf16(af, bfr, oacc[ti], 0, 0, 0);
    }
  }

  // C/D layout: col = lane&15, row = (lane>>4)*4 + reg
#pragma unroll
  for (int ti = 0; ti < 4; ti++) {
    int t = wave * 4 + ti;
    int n = t * 16 + mr;
    float b = bl[n];
#pragma unroll
    for (int reg = 0; reg < 4; reg++) {
      int j = base + quad * 4 + reg;
      if (j < U) h[j * HIDF + n] = fmaxf(oacc[ti][reg] + b, 0.0f);
    }
  }
}

// ---------------- layer 1: 2-wave float4 gather-mean + split dense + log_softmax ----------------
// h is compact; esrc1 already holds compact ids; map[i]=i for i<4096 (targets all used).
// Wave wv gathers edge range [wv*n/2 .. ), dense loop split over k-halves; LDS combine.
__global__ __launch_bounds__(128) void final_fused(
    const float* __restrict__ h, const int* __restrict__ off1,
    const int* __restrict__ esrc1, const float* __restrict__ Wl,
    const float* __restrict__ bl, const float* __restrict__ Wr,
    float* __restrict__ out) {
  __shared__ float a_ws[2][256];
  __shared__ float a_s[256];
  __shared__ float h_s[256];
  __shared__ float pacc[2][64];
  const int i = blockIdx.x;
  const int tid = threadIdx.x;
  const int wv = __builtin_amdgcn_readfirstlane(tid >> 6);
  const int lane = tid & 63;

  int s0 = __builtin_amdgcn_readfirstlane(off1[i]);
  int n  = __builtin_amdgcn_readfirstlane(off1[i + 1]) - s0;
  const int* e = esrc1 + s0;
  const float4* h4 = (const float4*)h;   // row = 64 float4

  // wave-split gather: wave0 edges [0, nh), wave1 [nh, n)
  const int nh = n >> 1;
  const int lo = wv ? nh : 0;
  const int hi = wv ? n : nh;
  float ax = 0.f, ay = 0.f, az = 0.f, aw = 0.f;
  int j = lo;
  for (; j + 4 <= hi; j += 4) {
    float4 v[4];
#pragma unroll
    for (int u = 0; u < 4; u++) v[u] = h4[e[j + u] * 64 + lane];
#pragma unroll
    for (int u = 0; u < 4; u++) {
      ax += v[u].x; ay += v[u].y; az += v[u].z; aw += v[u].w;
    }
  }
  for (; j < hi; j++) {
    float4 v = h4[e[j] * 64 + lane];
    ax += v.x; ay += v.y; az += v.z; aw += v.w;
  }
  float4 am; am.x = ax; am.y = ay; am.z = az; am.w = aw;
  ((float4*)a_ws[wv])[lane] = am;
  if (wv == 0) ((float4*)h_s)[lane] = h4[i * 64 + lane];
  __syncthreads();

  // combine wave partials -> mean (128 threads x 2 entries)
  float rinv = 1.f / fmaxf((float)n, 1.f);
  a_s[tid] = (a_ws[0][tid] + a_ws[1][tid]) * rinv;
  a_s[tid + 128] = (a_ws[0][tid + 128] + a_ws[1][tid + 128]) * rinv;
  __syncthreads();

  // dense: wave wv covers k in [wv*128, wv*128+128)
  {
    float acc = (wv == 0 && lane < OUTF) ? bl[lane] : 0.f;
    if (lane < OUTF) {
      const int k0 = wv * 128;
#pragma unroll 4
      for (int k = k0; k < k0 + 128; k++)
        acc += a_s[k] * Wl[k * OUTF + lane] + h_s[k] * Wr[k * OUTF + lane];
    }
    pacc[wv][lane] = acc;
  }
  __syncthreads();

  if (wv == 0) {
    float val = (lane < OUTF) ? (pacc[0][lane] + pacc[1][lane]) : -INFINITY;
    float mx = val;
    for (int off = 32; off >= 1; off >>= 1) mx = fmaxf(mx, __shfl_xor(mx, off, 64));
    float ex = (lane < OUTF) ? expf(val - mx) : 0.0f;
    float ssum = ex;
    for (int off = 32; off >= 1; off >>= 1) ssum += __shfl_xor(ssum, off, 64);
    if (lane < OUTF) out[i * OUTF + lane] = val - mx - logf(ssum);
  }
}

extern "C" void kernel_launch(void* const* d_in, const int* in_sizes, int n_in,
                              void* d_out, int out_size, void* d_ws, size_t ws_size,
                              hipStream_t stream) {
  const float* x   = (const float*)d_in[0];
  const float* Wl0 = (const float*)d_in[1];
  const float* bl0 = (const float*)d_in[2];
  const float* Wr0 = (const float*)d_in[3];
  const float* Wl1 = (const float*)d_in[4];
  const float* bl1 = (const float*)d_in[5];
  const float* Wr1 = (const float*)d_in[6];
  const int* src0  = (const int*)d_in[7];
  const int* dst0  = (const int*)d_in[8];
  const int* src1  = (const int*)d_in[9];
  const int* dst1  = (const int*)d_in[10];
  float* out = (float*)d_out;

  // workspace layout (bytes):
  //   hist0  @ 0          200,000
  //   hist1  @ 200,064     16,384
  //   used   @ 216,448    200,000   (memset covers [0, 416,448) only)
  //   esrc0p @ 416,448  6,800,000   (pad sentinels written by scanapply_k)
  //   poff   @ 7,216,448  200,068
  //   cntc   @ 7,416,576  200,064
  //   rowof  @ 7,616,640  200,064
  //   map    @ 7,816,704  200,000
  //   cur0   @ 8,016,704  200,000
  //   off1   @ 8,216,704   16,388
  //   cur1   @ 8,233,152   16,384
  //   esrc1  @ 8,249,536  163,840
  //   Ucnt   @ 8,413,376       64
  //   blkpc  @ 8,413,440    1,024
  //   blku   @ 8,414,464    1,024
  //   blk1   @ 8,415,488      128
  //   h      @ 8,416,640 51,200,000 (end 59,616,640)
  //   Wf0    @ 59,616,640   131,072 (end 59,747,712)
  char* ws = (char*)d_ws;
  int* hist0 = (int*)(ws);
  int* hist1 = (int*)(ws + 200064);
  int* used  = (int*)(ws + 216448);
  int* esrc0 = (int*)(ws + 416448);
  int* poff  = (int*)(ws + 7216448);
  int* cntc  = (int*)(ws + 7416576);
  int* rowof = (int*)(ws + 7616640);
  int* map   = (int*)(ws + 7816704);
  int* cur0  = (int*)(ws + 8016704);
  int* off1  = (int*)(ws + 8216704);
  int* cur1  = (int*)(ws + 8233152);
  int* esrc1 = (int*)(ws + 8249536);
  int* Ucnt  = (int*)(ws + 8413376);
  int* blkpc = (int*)(ws + 8413440);
  int* blku  = (int*)(ws + 8414464);
  int* blk1  = (int*)(ws + 8415488);
  float* h   = (float*)(ws + 8416640);
  u32* Wf0   = (u32*)(ws + 59616640);

  hipMemsetAsync(ws, 0, 416448, stream);

  prep_k<<<HIST_BLOCKS + PACKW_BLOCKS + USEDT_BLOCKS + USEDS_BLOCKS, 256, 0, stream>>>(
      dst0, dst1, src1, hist0, hist1, used, Wl0, Wr0, Wf0);
  scanpart_k<<<NB0 + NB1, 256, 0, stream>>>(hist0, hist1, used, blkpc, blku, blk1);
  scanapply_k<<<NB0 + NB1, 256, 0, stream>>>(hist0, hist1, used, blkpc, blku, blk1,
                                             poff, cntc, rowof, map, cur0, off1, cur1,
                                             Ucnt, esrc0);
  scatteridx_k<<<(E0V + E1V + 255) / 256, 256, 0, stream>>>(
      src0, dst0, src1, dst1, used, map, cur0, cur1, esrc0, esrc1);
  dense0_mfma<<<N1V / 16, 256, 0, stream>>>(x, poff, cntc, rowof, esrc0, Ucnt,
                                            Wf0, bl0, h);
  final_fused<<<N2V, 128, 0, stream>>>(h, off1, esrc1, Wl1, bl1, Wr1, out);
}